// Round 6
// baseline (431.216 us; speedup 1.0000x reference)
//
#include <hip/hip_runtime.h>

// ---------- types ----------
typedef __attribute__((ext_vector_type(8))) _Float16 half8;
typedef __attribute__((ext_vector_type(2))) __fp16 half2r;   // cvt_pkrtz return type
typedef __attribute__((ext_vector_type(4))) float f32x4;

#define AS1 __attribute__((address_space(1)))
#define AS3 __attribute__((address_space(3)))

union H2U { half2r h; unsigned int u; };
union Frag { half8 v; unsigned long long d[2]; };

__device__ __forceinline__ unsigned int pk(float a, float b) {
    H2U x; x.h = __builtin_amdgcn_cvt_pkrtz(a, b); return x.u;
}

__device__ __forceinline__ void gload_lds16(const void* g, void* l) {
    __builtin_amdgcn_global_load_lds((const AS1 unsigned int*)g,
                                     (AS3 unsigned int*)l, 16, 0, 0);
}

// ---------- problem constants ----------
// M = B*T = 32768, D_STATE = 1088, D_MODEL = 1024, D_LATENT = 128
// a16: LINEAR row-major f16, row = 2176 B (A never passes through LDS now).
// W1: row-major f16 2176 B/row with per-128B-window XOR swizzle
//     stored = n*2176 + (l & ~127) + ((l & 127) ^ ((n&7)<<4)), l = 2*k
//     (consumed from LDS -> needs the bank swizzle; pre-applied in global, m173)
#define ROWB    2176
#define WS2_OFF 2228224        // 1024 * 2176
#define W2_ROWB 256            // kv weights: unchanged 2-slab 128-B layout

// pick the fused-add source for 64-f32 slab ks (0..16)
__device__ __forceinline__ void pick_w(int ks, const float* wsp, const float* whp,
                                       const float* whs, const float* wtg,
                                       const float*& wbase, int& wstr, int& wko) {
    if (ks < 8)       { wbase = wsp; wstr = 512; wko = ks * 64; }
    else if (ks < 12) { wbase = whp; wstr = 256; wko = ks * 64 - 512; }
    else if (ks < 16) { wbase = whs; wstr = 256; wko = ks * 64 - 768; }
    else              { wbase = wtg; wstr = 64;  wko = 0; }
}

// ============ prologue: convert weights to f16 ============
__global__ __launch_bounds__(256) void prep_w(const float* __restrict__ Wr,
                                              const float* __restrict__ Wk,
                                              const float* __restrict__ Wv,
                                              char* __restrict__ ws) {
    int id = blockIdx.x * 256 + threadIdx.x;
    if (id < 272 * 1024) {                       // W_read: 1024 x 1088, XOR-in-window
        int n = id / 272;
        int k = (id % 272) * 4;
        f32x4 w = *(const f32x4*)(Wr + (size_t)n * 1088 + k);
        uint2 q; q.x = pk(w.x, w.y); q.y = pk(w.z, w.w);
        int l = k * 2;                           // byte within row (8-aligned)
        size_t off = (size_t)n * ROWB + (l & ~127)
                   + ((l & 127) ^ ((n & 7) << 4));
        *(uint2*)(ws + off) = q;
    } else {                                     // Wk|Wv combined: 2048 x 128 (unchanged)
        int j = id - 272 * 1024;
        int r = j >> 5;                          // 0..2047
        int k = (j & 31) << 2;                   // 0..124
        const float* src = (r < 1024) ? (Wk + (size_t)r * 128 + k)
                                      : (Wv + (size_t)(r - 1024) * 128 + k);
        f32x4 w = *(const f32x4*)src;
        uint2 q; q.x = pk(w.x, w.y); q.y = pk(w.z, w.w);
        size_t off = WS2_OFF + (size_t)r * W2_ROWB + ((k >> 6) << 7)
                   + (((k & 63) << 1) ^ ((r & 7) << 4));
        *(uint2*)(ws + off) = q;
    }
}

// ============ pass 1: Af16[m][k] = cvt(S + w), LINEAR ============
__global__ __launch_bounds__(256)
void fuse_a(const float* __restrict__ S, const float* __restrict__ wsp,
            const float* __restrict__ whp, const float* __restrict__ whs,
            const float* __restrict__ wtg, char* __restrict__ a16) {
    int u = blockIdx.x * 256 + threadIdx.x;
    int row = u / 272;
    int rem = u % 272;
    int ks = rem >> 4;
    int k4 = (rem & 15) << 2;                    // 0..60 within 64-f32 slab

    const float* wbase; int wstr, wko;
    pick_w(ks, wsp, whp, whs, wtg, wbase, wstr, wko);

    f32x4 s4 = *(const f32x4*)(S + (size_t)row * 1088 + ks * 64 + k4);
    f32x4 w4 = *(const f32x4*)(wbase + (size_t)row * wstr + wko + k4);
    uint2 q; q.x = pk(s4.x + w4.x, s4.y + w4.y);
             q.y = pk(s4.z + w4.z, s4.w + w4.w);
    *(uint2*)(a16 + (size_t)row * ROWB + (size_t)(ks * 64 + k4) * 2) = q;
}

// ============ GEMM1: out = Af16 @ W_read^T — B-resident streaming ============
// Block: 64 cols x 1024 rows. B (64 rows of W1 = 139,264 B contiguous) staged
// into LDS ONCE; K-loop has NO barriers, NO LDS for A: each wave streams its
// 128 A-rows' fragments global->VGPR (L1/L2-served) and issues MFMA. Waves are
// independent -> latency hidden by ILP (unrolled loop) + 2 waves/SIMD.
__global__ __launch_bounds__(512, 2)
void gemm_read(const char* __restrict__ a16, const char* __restrict__ wws,
               float* __restrict__ out) {
    __shared__ char Bl[139264];                  // 64 x 2176 B (swizzled in-window)

    int bid = blockIdx.x;
    int wg   = (bid & 7) * 64 + (bid >> 3);      // bijective XCD swizzle (512%8==0)
    int mg = wg >> 4, nb = wg & 15;              // 32 m-groups x 16 n-blocks
    int n0 = nb << 6;                            // 64 output cols

    int tid = threadIdx.x;
    int lane = tid & 63, wid = tid >> 6;
    int lp = lane & 15, lg = lane >> 4;
    int row0 = (mg << 10) + (wid << 7);          // wave's 128 rows

    // ---- stage B: flat 139,264-B copy (rows n0..n0+63 contiguous in wws)
    {
        const char* gb = wws + (size_t)n0 * ROWB;
        #pragma unroll
        for (int c = 0; c < 17; ++c) {
            int s = c * 8192 + tid * 16;
            gload_lds16(gb + s, Bl + s);
        }
    }
    asm volatile("s_waitcnt vmcnt(0)" ::: "memory");
    __syncthreads();

    f32x4 acc[8][4] = {};
    const char* arow = a16 + (size_t)row0 * ROWB + lg * 8;

    // ---- K-loop: 34 halves of K=32, barrier-free
    #pragma unroll 2
    for (int h = 0; h < 34; ++h) {
        Frag af[8], bf[4];
        #pragma unroll
        for (int f = 0; f < 8; ++f) {
            const char* p = arow + (size_t)(f * 16 + lp) * ROWB + h * 64;
            af[f].d[0] = *(const unsigned long long*)(p);
            af[f].d[1] = *(const unsigned long long*)(p + 32);
        }
        #pragma unroll
        for (int f = 0; f < 4; ++f) {
            int rb = f * 16 + lp;                // local B row (output col)
            int x  = (rb & 7) << 4;
            int l0 = h * 64 + lg * 8;            // logical byte in row
            int l1 = l0 + 32;                    // same 128-B window (lg<4)
            bf[f].d[0] = *(const unsigned long long*)(Bl + rb * ROWB + (l0 & ~127) + ((l0 & 127) ^ x));
            bf[f].d[1] = *(const unsigned long long*)(Bl + rb * ROWB + (l1 & ~127) + ((l1 & 127) ^ x));
        }
        #pragma unroll
        for (int i = 0; i < 8; ++i)
            #pragma unroll
            for (int j = 0; j < 4; ++j)
                acc[i][j] = __builtin_amdgcn_mfma_f32_16x16x32_f16(af[i].v, bf[j].v, acc[i][j], 0, 0, 0);
    }

    // ---- epilogue: C[row = row0+i*16+lg*4+r][col = n0+j*16+lp]
    #pragma unroll
    for (int i = 0; i < 8; ++i)
        #pragma unroll
        for (int j = 0; j < 4; ++j) {
            int row = row0 + i * 16 + (lg << 2);
            int col = n0 + j * 16 + lp;
            float* p = out + (size_t)row * 1024 + col;
            #pragma unroll
            for (int r = 0; r < 4; ++r) p[(size_t)r * 1024] = acc[i][j][r];
        }
}

// ============ GEMM2: k = latent@Wk^T, v = latent@Wv^T (R0-identical) ====
__global__ __launch_bounds__(256, 2)
void gemm_kv(const float* __restrict__ lat, const char* __restrict__ ws2,
             float* __restrict__ outk, float* __restrict__ outv) {
    __shared__ char lds[32768];
    char* Al = lds;
    char* Bl = lds + 16384;

    int bid = blockIdx.x;
    int wg   = (bid & 7) * 512 + (bid >> 3);     // 4096 % 8 == 0
    int mblk = wg >> 4, nb = wg & 15;
    int m0 = mblk << 7;
    int nrow0 = nb << 7;                          // row in combined Wk|Wv
    float* out = (nb < 8) ? outk : outv;
    int n0 = (nb & 7) << 7;

    int tid = threadIdx.x;
    int lane = tid & 63, wid = tid >> 6;
    int wm = (wid >> 1) << 6, wn = (wid & 1) << 6;
    int lp = lane & 15, lg = lane >> 4;

    f32x4 acc[4][4] = {};

    for (int ks = 0; ks < 2; ++ks) {
        __syncthreads();
        {
            const char* wrow = ws2 + (size_t)nrow0 * W2_ROWB + ks * 128;
            #pragma unroll
            for (int c = 0; c < 4; ++c) {
                int s = c * 4096 + wid * 1024 + lane * 16;
                int n = s >> 7, cb = s & 127;
                gload_lds16(wrow + (size_t)n * W2_ROWB + cb,
                            Bl + c * 4096 + wid * 1024);
            }
        }
        #pragma unroll
        for (int i = 0; i < 8; ++i) {
            int u = i * 256 + tid;
            int row = u >> 4;
            int k4 = (u & 15) << 2;
            f32x4 s4 = *(const f32x4*)(lat + (size_t)(m0 + row) * 128 + ks * 64 + k4);
            uint2 q; q.x = pk(s4.x, s4.y); q.y = pk(s4.z, s4.w);
            *(uint2*)(Al + (row << 7) + ((k4 << 1) ^ ((row & 7) << 4))) = q;
        }
        __syncthreads();

        #pragma unroll
        for (int b = 0; b < 2; ++b) {
            Frag af[4], bf[4];
            #pragma unroll
            for (int f = 0; f < 4; ++f) {
                int ra = wm + f * 16 + lp;  int xa = (ra & 7) << 4;
                af[f].d[0] = *(const unsigned long long*)(Al + (ra << 7) + ((b * 64 + lg * 8) ^ xa));
                af[f].d[1] = *(const unsigned long long*)(Al + (ra << 7) + ((b * 64 + 32 + lg * 8) ^ xa));
                int rb = wn + f * 16 + lp;  int xb = (rb & 7) << 4;
                bf[f].d[0] = *(const unsigned long long*)(Bl + (rb << 7) + ((b * 64 + lg * 8) ^ xb));
                bf[f].d[1] = *(const unsigned long long*)(Bl + (rb << 7) + ((b * 64 + 32 + lg * 8) ^ xb));
            }
            #pragma unroll
            for (int i = 0; i < 4; ++i)
                #pragma unroll
                for (int j = 0; j < 4; ++j)
                    acc[i][j] = __builtin_amdgcn_mfma_f32_16x16x32_f16(af[i].v, bf[j].v, acc[i][j], 0, 0, 0);
        }
    }

    #pragma unroll
    for (int i = 0; i < 4; ++i)
        #pragma unroll
        for (int j = 0; j < 4; ++j) {
            int row = m0 + wm + i * 16 + (lg << 2);
            int col = n0 + wn + j * 16 + lp;
            float* p = out + (size_t)row * 1024 + col;
            #pragma unroll
            for (int r = 0; r < 4; ++r) p[(size_t)r * 1024] = acc[i][j][r];
        }
}

// ============ host ============
extern "C" void kernel_launch(void* const* d_in, const int* in_sizes, int n_in,
                              void* d_out, int out_size, void* d_ws, size_t ws_size,
                              hipStream_t stream) {
    const float* S   = (const float*)d_in[0];
    const float* wsp = (const float*)d_in[1];
    const float* whp = (const float*)d_in[2];
    const float* whs = (const float*)d_in[3];
    const float* wtg = (const float*)d_in[4];
    const float* Wr  = (const float*)d_in[5];
    // d_in[6] = cache: fully overwritten by latent -> dead input
    const float* lat = (const float*)d_in[7];
    const float* Wk  = (const float*)d_in[8];
    const float* Wv  = (const float*)d_in[9];
    float* out = (float*)d_out;
    char*  ws  = (char*)d_ws;

    // Af16 scratch lives in the v-region of d_out (128 MB >= 71 MB);
    // gemm_kv overwrites it afterwards (stream-ordered, deterministic).
    char* a16 = (char*)(out + 67108864ull);

    hipLaunchKernelGGL(prep_w, dim3(1344), dim3(256), 0, stream, Wr, Wk, Wv, ws);
    hipLaunchKernelGGL(fuse_a, dim3(34816), dim3(256), 0, stream,
                       S, wsp, whp, whs, wtg, a16);
    hipLaunchKernelGGL(gemm_read, dim3(512), dim3(512), 0, stream,
                       a16, ws, out);
    hipLaunchKernelGGL(gemm_kv, dim3(4096), dim3(256), 0, stream,
                       lat, ws + WS2_OFF, out + 33554432ull, out + 67108864ull);
}

// Round 7
// 254.982 us; speedup vs baseline: 1.6912x; 1.6912x over previous
//
#include <hip/hip_runtime.h>

// ---------- types ----------
typedef __attribute__((ext_vector_type(8))) _Float16 half8;
typedef __attribute__((ext_vector_type(2))) __fp16 half2r;   // cvt_pkrtz return type
typedef __attribute__((ext_vector_type(4))) float f32x4;

#define AS1 __attribute__((address_space(1)))
#define AS3 __attribute__((address_space(3)))

union H2U { half2r h; unsigned int u; };
union Frag { half8 v; unsigned long long d[2]; };

__device__ __forceinline__ unsigned int pk(float a, float b) {
    H2U x; x.h = __builtin_amdgcn_cvt_pkrtz(a, b); return x.u;
}

__device__ __forceinline__ void gload_lds16(const void* g, void* l) {
    __builtin_amdgcn_global_load_lds((const AS1 unsigned int*)g,
                                     (AS3 unsigned int*)l, 16, 0, 0);
}

// ---------- problem constants ----------
// M = B*T = 32768, D_STATE = 1088, D_MODEL = 1024, D_LATENT = 128
//
// a16 / W1 layout ("LDS-image" panels): data grouped as (panel p of 128 rows,
// K-tile t of 64 elems) -> one 16 KB block at offset ((p*17 + t) << 14).
// Within a block, row r (0..127), k-in-tile kt (0..63):
//   kh = kt>>5, k32 = kt&31, u = (k32&15)>>2, pos8 = (k32>>4)<<3
//   byte = (r<<7) + ((((kh<<2)|u) ^ ((r>>1)&7)) << 4) + pos8
// This packs each MFMA fragment (lane's 8 f16) into ONE 16-B unit, XOR-spread
// so a 16-lane frag read covers all 8 16-B slots (2 lanes/slot = free, m136).
// Blocks are staged to LDS as flat linear copies (gload_lds-compatible, m173).
#define WS2_OFF 2228224        // = 1024 rows * 2176 B  (W1 total size, unchanged)
#define W2_ROWB 256            // kv weights: unchanged 2-slab 128-B layout

// pick the fused-add source for 64-f32 slab ks (0..16)
__device__ __forceinline__ void pick_w(int ks, const float* wsp, const float* whp,
                                       const float* whs, const float* wtg,
                                       const float*& wbase, int& wstr, int& wko) {
    if (ks < 8)       { wbase = wsp; wstr = 512; wko = ks * 64; }
    else if (ks < 12) { wbase = whp; wstr = 256; wko = ks * 64 - 512; }
    else if (ks < 16) { wbase = whs; wstr = 256; wko = ks * 64 - 768; }
    else              { wbase = wtg; wstr = 64;  wko = 0; }
}

// packed-frag address within a 16-KB panel-tile block
__device__ __forceinline__ size_t pf_addr(int r, int kt) {
    int kh = kt >> 5, k32 = kt & 31;
    int u = (k32 & 15) >> 2, pos8 = (k32 >> 4) << 3;
    return ((size_t)r << 7) + ((size_t)((((kh << 2) | u) ^ ((r >> 1) & 7)) << 4)) + pos8;
}

// ============ prologue: convert weights to f16 ============
__global__ __launch_bounds__(256) void prep_w(const float* __restrict__ Wr,
                                              const float* __restrict__ Wk,
                                              const float* __restrict__ Wv,
                                              char* __restrict__ ws) {
    int id = blockIdx.x * 256 + threadIdx.x;
    if (id < 272 * 1024) {                       // W_read: 1024 x 1088, packed-frag
        int n = id / 272;
        int k = (id % 272) * 4;
        f32x4 w = *(const f32x4*)(Wr + (size_t)n * 1088 + k);
        uint2 q; q.x = pk(w.x, w.y); q.y = pk(w.z, w.w);
        int t = k >> 6;
        size_t off = ((size_t)((n >> 7) * 17 + t) << 14) + pf_addr(n & 127, k & 63);
        *(uint2*)(ws + off) = q;
    } else {                                     // Wk|Wv combined: 2048 x 128 (unchanged)
        int j = id - 272 * 1024;
        int r = j >> 5;                          // 0..2047
        int k = (j & 31) << 2;                   // 0..124
        const float* src = (r < 1024) ? (Wk + (size_t)r * 128 + k)
                                      : (Wv + (size_t)(r - 1024) * 128 + k);
        f32x4 w = *(const f32x4*)src;
        uint2 q; q.x = pk(w.x, w.y); q.y = pk(w.z, w.w);
        size_t off = WS2_OFF + (size_t)r * W2_ROWB + ((k >> 6) << 7)
                   + (((k & 63) << 1) ^ ((r & 7) << 4));
        *(uint2*)(ws + off) = q;
    }
}

// ============ pass 1: Af16[m][k] = cvt(S + w), packed-frag panel-tile blocks ==
__global__ __launch_bounds__(256)
void fuse_a(const float* __restrict__ S, const float* __restrict__ wsp,
            const float* __restrict__ whp, const float* __restrict__ whs,
            const float* __restrict__ wtg, char* __restrict__ a16) {
    int u = blockIdx.x * 256 + threadIdx.x;
    int row = u / 272;
    int rem = u % 272;
    int ks = rem >> 4;                           // slab == K-tile (both 64 wide)
    int k4 = (rem & 15) << 2;                    // 0..60 within tile

    const float* wbase; int wstr, wko;
    pick_w(ks, wsp, whp, whs, wtg, wbase, wstr, wko);

    f32x4 s4 = *(const f32x4*)(S + (size_t)row * 1088 + ks * 64 + k4);
    f32x4 w4 = *(const f32x4*)(wbase + (size_t)row * wstr + wko + k4);
    uint2 q; q.x = pk(s4.x + w4.x, s4.y + w4.y);
             q.y = pk(s4.z + w4.z, s4.w + w4.w);
    size_t off = ((size_t)((row >> 7) * 17 + ks) << 14) + pf_addr(row & 127, k4);
    *(uint2*)(a16 + off) = q;
}

// ============ GEMM1: out = Af16 @ W_read^T — m201-style 4-phase/K-tile ========
// BM=BN=256, BK=64, 8 waves (2M x 4N), wave tile 128x64.
// LDS: 2 dbuf x 64 KB; each buf = {A-half0, A-half1, B-half0, B-half1} x 16 KB.
// Per phase: pre-barrier ds_read of one reg subtile (4-8 b128) + stage one
// half-tile of tile t+1 (2 gload_lds) -> barrier -> 16 MFMA (setprio) -> barrier.
// vmcnt(2) ONCE per tile at phase 0: retires the previous tile's 8 loads while
// the 2 just-issued stay in flight (counted, never drained in the loop — T4).
__global__ __launch_bounds__(512, 2)
void gemm_read(const char* __restrict__ a16, const char* __restrict__ wws,
               float* __restrict__ out) {
    extern __shared__ char lds[];                // 131072 B

    int bid = blockIdx.x;
    int wg   = (bid & 7) * 64 + (bid >> 3);      // bijective XCD swizzle (512%8==0)
    int mblk = wg >> 2, nblk = wg & 3;
    int m0 = mblk << 8, n0 = nblk << 8;

    int tid = threadIdx.x;
    int lane = tid & 63, wid = tid >> 6;
    int wm = (wid >> 2) << 7, wn = (wid & 3) << 6;   // wave tile: 128x64
    int lp = lane & 15, lg = lane >> 4;

    int aoff = (wid >> 2) * 16384;               // wave's A-half region
    int boff = 32768 + (wn >> 7) * 16384;        // wave's B-half region
    int cb64 = wn & 64;                          // col base within B-half

    // half-tile sources (each ((p*17)+t)<<14 block, flat 16 KB)
    const char* srcH[4];
    srcH[0] = a16 + ((size_t)((m0 >> 7) * 17) << 14);
    srcH[1] = srcH[0] + (17 << 14);
    srcH[2] = wws + ((size_t)((n0 >> 7) * 17) << 14);
    srcH[3] = srcH[2] + (17 << 14);

    f32x4 acc[8][4] = {};
    Frag af[4], bf[4];

#define STAGE(T, H, DB) do {                                               \
        const char* s_ = srcH[H] + ((size_t)(T) << 14);                    \
        char* d_ = lds + (DB) + (H) * 16384;                               \
        gload_lds16(s_ + tid * 16, d_ + tid * 16);                         \
        gload_lds16(s_ + 8192 + tid * 16, d_ + 8192 + tid * 16);           \
    } while (0)

#define LOADA(MH, KH, BB) do {                                             \
        _Pragma("unroll")                                                  \
        for (int f = 0; f < 4; ++f) {                                      \
            int r_ = (MH) * 64 + f * 16 + lp;                              \
            af[f] = *(const Frag*)(lds + (BB) + aoff + (r_ << 7)           \
                     + ((((((KH) << 2) | lg) ^ ((r_ >> 1) & 7))) << 4));   \
        }                                                                  \
    } while (0)

#define LOADB(KH, BB) do {                                                 \
        _Pragma("unroll")                                                  \
        for (int g = 0; g < 4; ++g) {                                      \
            int c_ = cb64 + g * 16 + lp;                                   \
            bf[g] = *(const Frag*)(lds + (BB) + boff + (c_ << 7)           \
                     + ((((((KH) << 2) | lg) ^ ((c_ >> 1) & 7))) << 4));   \
        }                                                                  \
    } while (0)

#define MFMA16(MH) do {                                                    \
        __builtin_amdgcn_s_setprio(1);                                     \
        _Pragma("unroll")                                                  \
        for (int f = 0; f < 4; ++f)                                        \
            _Pragma("unroll")                                              \
            for (int g = 0; g < 4; ++g)                                    \
                acc[(MH) * 4 + f][g] = __builtin_amdgcn_mfma_f32_16x16x32_f16( \
                    af[f].v, bf[g].v, acc[(MH) * 4 + f][g], 0, 0, 0);      \
        __builtin_amdgcn_s_setprio(0);                                     \
    } while (0)

    // prologue: stage tile 0 fully into buf 0 (8 loads/thread outstanding)
    STAGE(0, 0, 0); STAGE(0, 1, 0); STAGE(0, 2, 0); STAGE(0, 3, 0);

    for (int t = 0; t < 16; ++t) {
        int BB = (t & 1) << 16;
        int NB = BB ^ 65536;
        // ---- phase 0 (mh=0, kh=0)
        STAGE(t + 1, 0, NB);
        asm volatile("s_waitcnt vmcnt(2)" ::: "memory");  // tile t landed; 2 fly on
        __builtin_amdgcn_s_barrier();
        LOADB(0, BB); LOADA(0, 0, BB);
        MFMA16(0);
        __builtin_amdgcn_s_barrier();
        // ---- phase 1 (mh=1, kh=0): ds_read pre-barrier (data resident)
        LOADA(1, 0, BB);
        STAGE(t + 1, 1, NB);
        __builtin_amdgcn_s_barrier();
        MFMA16(1);
        __builtin_amdgcn_s_barrier();
        // ---- phase 2 (mh=0, kh=1)
        LOADB(1, BB); LOADA(0, 1, BB);
        STAGE(t + 1, 2, NB);
        __builtin_amdgcn_s_barrier();
        MFMA16(0);
        __builtin_amdgcn_s_barrier();
        // ---- phase 3 (mh=1, kh=1)
        LOADA(1, 1, BB);
        STAGE(t + 1, 3, NB);
        __builtin_amdgcn_s_barrier();
        MFMA16(1);
        __builtin_amdgcn_s_barrier();
    }
    // ---- tail: tile 16 (in buf 0), nothing left to stage
    {
        const int BB = 0;
        asm volatile("s_waitcnt vmcnt(0)" ::: "memory");
        __builtin_amdgcn_s_barrier();
        LOADB(0, BB); LOADA(0, 0, BB); MFMA16(0);
        __builtin_amdgcn_s_barrier();
        LOADA(1, 0, BB); MFMA16(1);
        __builtin_amdgcn_s_barrier();
        LOADB(1, BB); LOADA(0, 1, BB); MFMA16(0);
        __builtin_amdgcn_s_barrier();
        LOADA(1, 1, BB); MFMA16(1);
    }

    // epilogue: C[row = m0+wm+i*16+lg*4+r][col = n0+wn+j*16+lp]
    #pragma unroll
    for (int i = 0; i < 8; ++i)
        #pragma unroll
        for (int j = 0; j < 4; ++j) {
            int row = m0 + wm + i * 16 + (lg << 2);
            int col = n0 + wn + j * 16 + lp;
            float* p = out + (size_t)row * 1024 + col;
            #pragma unroll
            for (int r = 0; r < 4; ++r) p[(size_t)r * 1024] = acc[i][j][r];
        }
#undef STAGE
#undef LOADA
#undef LOADB
#undef MFMA16
}

// ============ GEMM2: k = latent@Wk^T, v = latent@Wv^T (R0-identical) ====
__global__ __launch_bounds__(256, 2)
void gemm_kv(const float* __restrict__ lat, const char* __restrict__ ws2,
             float* __restrict__ outk, float* __restrict__ outv) {
    __shared__ char lds[32768];
    char* Al = lds;
    char* Bl = lds + 16384;

    int bid = blockIdx.x;
    int wg   = (bid & 7) * 512 + (bid >> 3);     // 4096 % 8 == 0
    int mblk = wg >> 4, nb = wg & 15;
    int m0 = mblk << 7;
    int nrow0 = nb << 7;                          // row in combined Wk|Wv
    float* out = (nb < 8) ? outk : outv;
    int n0 = (nb & 7) << 7;

    int tid = threadIdx.x;
    int lane = tid & 63, wid = tid >> 6;
    int wm = (wid >> 1) << 6, wn = (wid & 1) << 6;
    int lp = lane & 15, lg = lane >> 4;

    f32x4 acc[4][4] = {};

    for (int ks = 0; ks < 2; ++ks) {
        __syncthreads();
        {
            const char* wrow = ws2 + (size_t)nrow0 * W2_ROWB + ks * 128;
            #pragma unroll
            for (int c = 0; c < 4; ++c) {
                int s = c * 4096 + wid * 1024 + lane * 16;
                int n = s >> 7, cb = s & 127;
                gload_lds16(wrow + (size_t)n * W2_ROWB + cb,
                            Bl + c * 4096 + wid * 1024);
            }
        }
        #pragma unroll
        for (int i = 0; i < 8; ++i) {
            int u = i * 256 + tid;
            int row = u >> 4;
            int k4 = (u & 15) << 2;
            f32x4 s4 = *(const f32x4*)(lat + (size_t)(m0 + row) * 128 + ks * 64 + k4);
            uint2 q; q.x = pk(s4.x, s4.y); q.y = pk(s4.z, s4.w);
            *(uint2*)(Al + (row << 7) + ((k4 << 1) ^ ((row & 7) << 4))) = q;
        }
        __syncthreads();

        #pragma unroll
        for (int b = 0; b < 2; ++b) {
            Frag af[4], bf[4];
            #pragma unroll
            for (int f = 0; f < 4; ++f) {
                int ra = wm + f * 16 + lp;  int xa = (ra & 7) << 4;
                af[f].d[0] = *(const unsigned long long*)(Al + (ra << 7) + ((b * 64 + lg * 8) ^ xa));
                af[f].d[1] = *(const unsigned long long*)(Al + (ra << 7) + ((b * 64 + 32 + lg * 8) ^ xa));
                int rb = wn + f * 16 + lp;  int xb = (rb & 7) << 4;
                bf[f].d[0] = *(const unsigned long long*)(Bl + (rb << 7) + ((b * 64 + lg * 8) ^ xb));
                bf[f].d[1] = *(const unsigned long long*)(Bl + (rb << 7) + ((b * 64 + 32 + lg * 8) ^ xb));
            }
            #pragma unroll
            for (int i = 0; i < 4; ++i)
                #pragma unroll
                for (int j = 0; j < 4; ++j)
                    acc[i][j] = __builtin_amdgcn_mfma_f32_16x16x32_f16(af[i].v, bf[j].v, acc[i][j], 0, 0, 0);
        }
    }

    #pragma unroll
    for (int i = 0; i < 4; ++i)
        #pragma unroll
        for (int j = 0; j < 4; ++j) {
            int row = m0 + wm + i * 16 + (lg << 2);
            int col = n0 + wn + j * 16 + lp;
            float* p = out + (size_t)row * 1024 + col;
            #pragma unroll
            for (int r = 0; r < 4; ++r) p[(size_t)r * 1024] = acc[i][j][r];
        }
}

// ============ host ============
extern "C" void kernel_launch(void* const* d_in, const int* in_sizes, int n_in,
                              void* d_out, int out_size, void* d_ws, size_t ws_size,
                              hipStream_t stream) {
    const float* S   = (const float*)d_in[0];
    const float* wsp = (const float*)d_in[1];
    const float* whp = (const float*)d_in[2];
    const float* whs = (const float*)d_in[3];
    const float* wtg = (const float*)d_in[4];
    const float* Wr  = (const float*)d_in[5];
    // d_in[6] = cache: fully overwritten by latent -> dead input
    const float* lat = (const float*)d_in[7];
    const float* Wk  = (const float*)d_in[8];
    const float* Wv  = (const float*)d_in[9];
    float* out = (float*)d_out;
    char*  ws  = (char*)d_ws;

    // allow >64 KB dynamic LDS for gemm_read (host-side, one-time)
    static bool lds_init = false;
    if (!lds_init) {
        hipFuncSetAttribute(reinterpret_cast<const void*>(gemm_read),
                            hipFuncAttributeMaxDynamicSharedMemorySize, 131072);
        lds_init = true;
    }

    // Af16 scratch lives in the v-region of d_out (128 MB >= 71 MB);
    // gemm_kv overwrites it afterwards (stream-ordered, deterministic).
    char* a16 = (char*)(out + 67108864ull);

    hipLaunchKernelGGL(prep_w, dim3(1344), dim3(256), 0, stream, Wr, Wk, Wv, ws);
    hipLaunchKernelGGL(fuse_a, dim3(34816), dim3(256), 0, stream,
                       S, wsp, whp, whs, wtg, a16);
    hipLaunchKernelGGL(gemm_read, dim3(512), dim3(512), 131072, stream,
                       a16, ws, out);
    hipLaunchKernelGGL(gemm_kv, dim3(4096), dim3(256), 0, stream,
                       lat, ws + WS2_OFF, out + 33554432ull, out + 67108864ull);
}

// Round 8
// 253.095 us; speedup vs baseline: 1.7038x; 1.0075x over previous
//
#include <hip/hip_runtime.h>

// ---------- types ----------
typedef __attribute__((ext_vector_type(8))) _Float16 half8;
typedef __attribute__((ext_vector_type(2))) __fp16 half2r;   // cvt_pkrtz return type
typedef __attribute__((ext_vector_type(4))) float f32x4;

#define AS1 __attribute__((address_space(1)))
#define AS3 __attribute__((address_space(3)))

union H2U { half2r h; unsigned int u; };
union Frag { half8 v; unsigned long long d[2]; };

__device__ __forceinline__ unsigned int pk(float a, float b) {
    H2U x; x.h = __builtin_amdgcn_cvt_pkrtz(a, b); return x.u;
}

__device__ __forceinline__ void gload_lds16(const void* g, void* l) {
    __builtin_amdgcn_global_load_lds((const AS1 unsigned int*)g,
                                     (AS3 unsigned int*)l, 16, 0, 0);
}

// ---------- problem constants ----------
// M = B*T = 32768, D_STATE = 1088, D_MODEL = 1024, D_LATENT = 128
//
// a16 / W1 layout ("LDS-image" panels): data grouped as (panel p of 128 rows,
// K-tile t of 64 elems) -> one 16 KB block at offset ((p*17 + t) << 14).
// Within a block, row r (0..127), k-in-tile kt (0..63):
//   kh = kt>>5, k32 = kt&31, u = (k32&15)>>2, pos8 = (k32>>4)<<3
//   byte = (r<<7) + ((((kh<<2)|u) ^ (r&7)) << 4) + pos8
// Packs each MFMA fragment (lane's 8 f16) into ONE 16-B slot. XOR key is r&7
// (NOT (r>>1)&7): a wave64 b128 read is served as 8 octs of 8 lanes; with
// lp = r&15, each oct has 8 CONSECUTIVE r values -> slots C^{0..7} = all 8
// distinct 16-B slots = all 32 banks -> conflict-free at the 8-sweep minimum.
// (R7 used (r>>1)&7: each oct covered only 4 slots -> 2-way serialization on
// every sweep; SQ_LDS_BANK_CONFLICT-dominated, ~9.1k cyc/tile.)
#define WS2_OFF 2228224        // = 1024 rows * 2176 B  (W1 total size, unchanged)
#define W2_ROWB 256            // kv weights: unchanged 2-slab 128-B layout

// pick the fused-add source for 64-f32 slab ks (0..16)
__device__ __forceinline__ void pick_w(int ks, const float* wsp, const float* whp,
                                       const float* whs, const float* wtg,
                                       const float*& wbase, int& wstr, int& wko) {
    if (ks < 8)       { wbase = wsp; wstr = 512; wko = ks * 64; }
    else if (ks < 12) { wbase = whp; wstr = 256; wko = ks * 64 - 512; }
    else if (ks < 16) { wbase = whs; wstr = 256; wko = ks * 64 - 768; }
    else              { wbase = wtg; wstr = 64;  wko = 0; }
}

// packed-frag address within a 16-KB panel-tile block
__device__ __forceinline__ size_t pf_addr(int r, int kt) {
    int kh = kt >> 5, k32 = kt & 31;
    int u = (k32 & 15) >> 2, pos8 = (k32 >> 4) << 3;
    return ((size_t)r << 7) + ((size_t)((((kh << 2) | u) ^ (r & 7)) << 4)) + pos8;
}

// ============ prologue: convert weights to f16 ============
__global__ __launch_bounds__(256) void prep_w(const float* __restrict__ Wr,
                                              const float* __restrict__ Wk,
                                              const float* __restrict__ Wv,
                                              char* __restrict__ ws) {
    int id = blockIdx.x * 256 + threadIdx.x;
    if (id < 272 * 1024) {                       // W_read: 1024 x 1088, packed-frag
        int n = id / 272;
        int k = (id % 272) * 4;
        f32x4 w = *(const f32x4*)(Wr + (size_t)n * 1088 + k);
        uint2 q; q.x = pk(w.x, w.y); q.y = pk(w.z, w.w);
        int t = k >> 6;
        size_t off = ((size_t)((n >> 7) * 17 + t) << 14) + pf_addr(n & 127, k & 63);
        *(uint2*)(ws + off) = q;
    } else {                                     // Wk|Wv combined: 2048 x 128 (unchanged)
        int j = id - 272 * 1024;
        int r = j >> 5;                          // 0..2047
        int k = (j & 31) << 2;                   // 0..124
        const float* src = (r < 1024) ? (Wk + (size_t)r * 128 + k)
                                      : (Wv + (size_t)(r - 1024) * 128 + k);
        f32x4 w = *(const f32x4*)src;
        uint2 q; q.x = pk(w.x, w.y); q.y = pk(w.z, w.w);
        size_t off = WS2_OFF + (size_t)r * W2_ROWB + ((k >> 6) << 7)
                   + (((k & 63) << 1) ^ ((r & 7) << 4));
        *(uint2*)(ws + off) = q;
    }
}

// ============ pass 1: Af16[m][k] = cvt(S + w), packed-frag panel-tile blocks ==
__global__ __launch_bounds__(256)
void fuse_a(const float* __restrict__ S, const float* __restrict__ wsp,
            const float* __restrict__ whp, const float* __restrict__ whs,
            const float* __restrict__ wtg, char* __restrict__ a16) {
    int u = blockIdx.x * 256 + threadIdx.x;
    int row = u / 272;
    int rem = u % 272;
    int ks = rem >> 4;                           // slab == K-tile (both 64 wide)
    int k4 = (rem & 15) << 2;                    // 0..60 within tile

    const float* wbase; int wstr, wko;
    pick_w(ks, wsp, whp, whs, wtg, wbase, wstr, wko);

    f32x4 s4 = *(const f32x4*)(S + (size_t)row * 1088 + ks * 64 + k4);
    f32x4 w4 = *(const f32x4*)(wbase + (size_t)row * wstr + wko + k4);
    uint2 q; q.x = pk(s4.x + w4.x, s4.y + w4.y);
             q.y = pk(s4.z + w4.z, s4.w + w4.w);
    size_t off = ((size_t)((row >> 7) * 17 + ks) << 14) + pf_addr(row & 127, k4);
    *(uint2*)(a16 + off) = q;
}

// ============ GEMM1: out = Af16 @ W_read^T — m201-style 4-phase/K-tile ========
// BM=BN=256, BK=64, 8 waves (2M x 4N), wave tile 128x64.
// LDS: 2 dbuf x 64 KB; each buf = {A-half0, A-half1, B-half0, B-half1} x 16 KB.
// Per phase: pre-barrier ds_read of one reg subtile + stage one half-tile of
// tile t+1 (2 gload_lds) -> barrier -> 16 MFMA (setprio) -> barrier.
// vmcnt(2) ONCE per tile at phase 0 (counted, never drained in loop — T4).
__global__ __launch_bounds__(512, 2)
void gemm_read(const char* __restrict__ a16, const char* __restrict__ wws,
               float* __restrict__ out) {
    extern __shared__ char lds[];                // 131072 B

    int bid = blockIdx.x;
    int wg   = (bid & 7) * 64 + (bid >> 3);      // bijective XCD swizzle (512%8==0)
    int mblk = wg >> 2, nblk = wg & 3;
    int m0 = mblk << 8, n0 = nblk << 8;

    int tid = threadIdx.x;
    int lane = tid & 63, wid = tid >> 6;
    int wm = (wid >> 2) << 7, wn = (wid & 3) << 6;   // wave tile: 128x64
    int lp = lane & 15, lg = lane >> 4;

    int aoff = (wid >> 2) * 16384;               // wave's A-half region
    int boff = 32768 + (wn >> 7) * 16384;        // wave's B-half region
    int cb64 = wn & 64;                          // col base within B-half

    // half-tile sources (each ((p*17)+t)<<14 block, flat 16 KB)
    const char* srcH[4];
    srcH[0] = a16 + ((size_t)((m0 >> 7) * 17) << 14);
    srcH[1] = srcH[0] + (17 << 14);
    srcH[2] = wws + ((size_t)((n0 >> 7) * 17) << 14);
    srcH[3] = srcH[2] + (17 << 14);

    f32x4 acc[8][4] = {};
    Frag af[4], bf[4];

#define STAGE(T, H, DB) do {                                               \
        const char* s_ = srcH[H] + ((size_t)(T) << 14);                    \
        char* d_ = lds + (DB) + (H) * 16384;                               \
        gload_lds16(s_ + tid * 16, d_ + tid * 16);                         \
        gload_lds16(s_ + 8192 + tid * 16, d_ + 8192 + tid * 16);           \
    } while (0)

#define LOADA(MH, KH, BB) do {                                             \
        _Pragma("unroll")                                                  \
        for (int f = 0; f < 4; ++f) {                                      \
            int r_ = (MH) * 64 + f * 16 + lp;                              \
            af[f] = *(const Frag*)(lds + (BB) + aoff + (r_ << 7)           \
                     + ((((((KH) << 2) | lg) ^ (r_ & 7))) << 4));          \
        }                                                                  \
    } while (0)

#define LOADB(KH, BB) do {                                                 \
        _Pragma("unroll")                                                  \
        for (int g = 0; g < 4; ++g) {                                      \
            int c_ = cb64 + g * 16 + lp;                                   \
            bf[g] = *(const Frag*)(lds + (BB) + boff + (c_ << 7)           \
                     + ((((((KH) << 2) | lg) ^ (c_ & 7))) << 4));          \
        }                                                                  \
    } while (0)

#define MFMA16(MH) do {                                                    \
        __builtin_amdgcn_s_setprio(1);                                     \
        _Pragma("unroll")                                                  \
        for (int f = 0; f < 4; ++f)                                        \
            _Pragma("unroll")                                              \
            for (int g = 0; g < 4; ++g)                                    \
                acc[(MH) * 4 + f][g] = __builtin_amdgcn_mfma_f32_16x16x32_f16( \
                    af[f].v, bf[g].v, acc[(MH) * 4 + f][g], 0, 0, 0);      \
        __builtin_amdgcn_s_setprio(0);                                     \
    } while (0)

    // prologue: stage tile 0 fully into buf 0 (8 loads/thread outstanding)
    STAGE(0, 0, 0); STAGE(0, 1, 0); STAGE(0, 2, 0); STAGE(0, 3, 0);

    for (int t = 0; t < 16; ++t) {
        int BB = (t & 1) << 16;
        int NB = BB ^ 65536;
        // ---- phase 0 (mh=0, kh=0)
        STAGE(t + 1, 0, NB);
        asm volatile("s_waitcnt vmcnt(2)" ::: "memory");  // tile t landed; 2 fly on
        __builtin_amdgcn_s_barrier();
        LOADB(0, BB); LOADA(0, 0, BB);
        MFMA16(0);
        __builtin_amdgcn_s_barrier();
        // ---- phase 1 (mh=1, kh=0): ds_read pre-barrier (data resident)
        LOADA(1, 0, BB);
        STAGE(t + 1, 1, NB);
        __builtin_amdgcn_s_barrier();
        MFMA16(1);
        __builtin_amdgcn_s_barrier();
        // ---- phase 2 (mh=0, kh=1)
        LOADB(1, BB); LOADA(0, 1, BB);
        STAGE(t + 1, 2, NB);
        __builtin_amdgcn_s_barrier();
        MFMA16(0);
        __builtin_amdgcn_s_barrier();
        // ---- phase 3 (mh=1, kh=1)
        LOADA(1, 1, BB);
        STAGE(t + 1, 3, NB);
        __builtin_amdgcn_s_barrier();
        MFMA16(1);
        __builtin_amdgcn_s_barrier();
    }
    // ---- tail: tile 16 (in buf 0), nothing left to stage
    {
        const int BB = 0;
        asm volatile("s_waitcnt vmcnt(0)" ::: "memory");
        __builtin_amdgcn_s_barrier();
        LOADB(0, BB); LOADA(0, 0, BB); MFMA16(0);
        __builtin_amdgcn_s_barrier();
        LOADA(1, 0, BB); MFMA16(1);
        __builtin_amdgcn_s_barrier();
        LOADB(1, BB); LOADA(0, 1, BB); MFMA16(0);
        __builtin_amdgcn_s_barrier();
        LOADA(1, 1, BB); MFMA16(1);
    }

    // epilogue: C[row = m0+wm+i*16+lg*4+r][col = n0+wn+j*16+lp]
    #pragma unroll
    for (int i = 0; i < 8; ++i)
        #pragma unroll
        for (int j = 0; j < 4; ++j) {
            int row = m0 + wm + i * 16 + (lg << 2);
            int col = n0 + wn + j * 16 + lp;
            float* p = out + (size_t)row * 1024 + col;
            #pragma unroll
            for (int r = 0; r < 4; ++r) p[(size_t)r * 1024] = acc[i][j][r];
        }
#undef STAGE
#undef LOADA
#undef LOADB
#undef MFMA16
}

// ============ GEMM2: k = latent@Wk^T, v = latent@Wv^T (R0-identical) ====
__global__ __launch_bounds__(256, 2)
void gemm_kv(const float* __restrict__ lat, const char* __restrict__ ws2,
             float* __restrict__ outk, float* __restrict__ outv) {
    __shared__ char lds[32768];
    char* Al = lds;
    char* Bl = lds + 16384;

    int bid = blockIdx.x;
    int wg   = (bid & 7) * 512 + (bid >> 3);     // 4096 % 8 == 0
    int mblk = wg >> 4, nb = wg & 15;
    int m0 = mblk << 7;
    int nrow0 = nb << 7;                          // row in combined Wk|Wv
    float* out = (nb < 8) ? outk : outv;
    int n0 = (nb & 7) << 7;

    int tid = threadIdx.x;
    int lane = tid & 63, wid = tid >> 6;
    int wm = (wid >> 1) << 6, wn = (wid & 1) << 6;
    int lp = lane & 15, lg = lane >> 4;

    f32x4 acc[4][4] = {};

    for (int ks = 0; ks < 2; ++ks) {
        __syncthreads();
        {
            const char* wrow = ws2 + (size_t)nrow0 * W2_ROWB + ks * 128;
            #pragma unroll
            for (int c = 0; c < 4; ++c) {
                int s = c * 4096 + wid * 1024 + lane * 16;
                int n = s >> 7, cb = s & 127;
                gload_lds16(wrow + (size_t)n * W2_ROWB + cb,
                            Bl + c * 4096 + wid * 1024);
            }
        }
        #pragma unroll
        for (int i = 0; i < 8; ++i) {
            int u = i * 256 + tid;
            int row = u >> 4;
            int k4 = (u & 15) << 2;
            f32x4 s4 = *(const f32x4*)(lat + (size_t)(m0 + row) * 128 + ks * 64 + k4);
            uint2 q; q.x = pk(s4.x, s4.y); q.y = pk(s4.z, s4.w);
            *(uint2*)(Al + (row << 7) + ((k4 << 1) ^ ((row & 7) << 4))) = q;
        }
        __syncthreads();

        #pragma unroll
        for (int b = 0; b < 2; ++b) {
            Frag af[4], bf[4];
            #pragma unroll
            for (int f = 0; f < 4; ++f) {
                int ra = wm + f * 16 + lp;  int xa = (ra & 7) << 4;
                af[f].d[0] = *(const unsigned long long*)(Al + (ra << 7) + ((b * 64 + lg * 8) ^ xa));
                af[f].d[1] = *(const unsigned long long*)(Al + (ra << 7) + ((b * 64 + 32 + lg * 8) ^ xa));
                int rb = wn + f * 16 + lp;  int xb = (rb & 7) << 4;
                bf[f].d[0] = *(const unsigned long long*)(Bl + (rb << 7) + ((b * 64 + lg * 8) ^ xb));
                bf[f].d[1] = *(const unsigned long long*)(Bl + (rb << 7) + ((b * 64 + 32 + lg * 8) ^ xb));
            }
            #pragma unroll
            for (int i = 0; i < 4; ++i)
                #pragma unroll
                for (int j = 0; j < 4; ++j)
                    acc[i][j] = __builtin_amdgcn_mfma_f32_16x16x32_f16(af[i].v, bf[j].v, acc[i][j], 0, 0, 0);
        }
    }

    #pragma unroll
    for (int i = 0; i < 4; ++i)
        #pragma unroll
        for (int j = 0; j < 4; ++j) {
            int row = m0 + wm + i * 16 + (lg << 2);
            int col = n0 + wn + j * 16 + lp;
            float* p = out + (size_t)row * 1024 + col;
            #pragma unroll
            for (int r = 0; r < 4; ++r) p[(size_t)r * 1024] = acc[i][j][r];
        }
}

// ============ host ============
extern "C" void kernel_launch(void* const* d_in, const int* in_sizes, int n_in,
                              void* d_out, int out_size, void* d_ws, size_t ws_size,
                              hipStream_t stream) {
    const float* S   = (const float*)d_in[0];
    const float* wsp = (const float*)d_in[1];
    const float* whp = (const float*)d_in[2];
    const float* whs = (const float*)d_in[3];
    const float* wtg = (const float*)d_in[4];
    const float* Wr  = (const float*)d_in[5];
    // d_in[6] = cache: fully overwritten by latent -> dead input
    const float* lat = (const float*)d_in[7];
    const float* Wk  = (const float*)d_in[8];
    const float* Wv  = (const float*)d_in[9];
    float* out = (float*)d_out;
    char*  ws  = (char*)d_ws;

    // allow >64 KB dynamic LDS for gemm_read (host-side, one-time)
    static bool lds_init = false;
    if (!lds_init) {
        hipFuncSetAttribute(reinterpret_cast<const void*>(gemm_read),
                            hipFuncAttributeMaxDynamicSharedMemorySize, 131072);
        lds_init = true;
    }

    // Af16 scratch lives in the v-region of d_out (128 MB >= 71 MB);
    // gemm_kv overwrites it afterwards (stream-ordered, deterministic).
    char* a16 = (char*)(out + 67108864ull);

    hipLaunchKernelGGL(prep_w, dim3(1344), dim3(256), 0, stream, Wr, Wk, Wv, ws);
    hipLaunchKernelGGL(fuse_a, dim3(34816), dim3(256), 0, stream,
                       S, wsp, whp, whs, wtg, a16);
    hipLaunchKernelGGL(gemm_read, dim3(512), dim3(512), 131072, stream,
                       a16, ws, out);
    hipLaunchKernelGGL(gemm_kv, dim3(4096), dim3(256), 0, stream,
                       lat, ws + WS2_OFF, out + 33554432ull, out + 67108864ull);
}

// Round 9
// 227.866 us; speedup vs baseline: 1.8924x; 1.1107x over previous
//
#include <hip/hip_runtime.h>

// ---------- types ----------
typedef __attribute__((ext_vector_type(8))) _Float16 half8;
typedef __attribute__((ext_vector_type(2))) __fp16 half2r;   // cvt_pkrtz return type
typedef __attribute__((ext_vector_type(4))) float f32x4;

#define AS1 __attribute__((address_space(1)))
#define AS3 __attribute__((address_space(3)))

union H2U { half2r h; unsigned int u; };
union Frag { half8 v; unsigned long long d[2]; };

__device__ __forceinline__ unsigned int pk(float a, float b) {
    H2U x; x.h = __builtin_amdgcn_cvt_pkrtz(a, b); return x.u;
}

__device__ __forceinline__ void gload_lds16(const void* g, void* l) {
    __builtin_amdgcn_global_load_lds((const AS1 unsigned int*)g,
                                     (AS3 unsigned int*)l, 16, 0, 0);
}

// ---------- problem constants ----------
// M = B*T = 32768, D_STATE = 1088, D_MODEL = 1024, D_LATENT = 128
// a16 / W1 layout: panel-tile 16 KB blocks at ((p*17 + t) << 14); within:
//   byte = (r<<7) + ((((kh<<2)|u) ^ (r&7)) << 4) + pos8   (see R8)
#define WS2_OFF 2228224        // = 1024 rows * 2176 B  (W1 total size)
#define WS2_SZ  524288         // 2048 rows * 256 B
#define W2_ROWB 256            // kv weights: 2-slab 128-B layout
#define A16_SZ  71303168ull    // 32768 * 2176

// pick the fused-add source for 64-f32 slab ks (0..16)
__device__ __forceinline__ void pick_w(int ks, const float* wsp, const float* whp,
                                       const float* whs, const float* wtg,
                                       const float*& wbase, int& wstr, int& wko) {
    if (ks < 8)       { wbase = wsp; wstr = 512; wko = ks * 64; }
    else if (ks < 12) { wbase = whp; wstr = 256; wko = ks * 64 - 512; }
    else if (ks < 16) { wbase = whs; wstr = 256; wko = ks * 64 - 768; }
    else              { wbase = wtg; wstr = 64;  wko = 0; }
}

// packed-frag address within a 16-KB panel-tile block
__device__ __forceinline__ size_t pf_addr(int r, int kt) {
    int kh = kt >> 5, k32 = kt & 31;
    int u = (k32 & 15) >> 2, pos8 = (k32 >> 4) << 3;
    return ((size_t)r << 7) + ((size_t)((((kh << 2) | u) ^ (r & 7)) << 4)) + pos8;
}

// ============ prologue: convert weights to f16 (R8-identical) ============
__global__ __launch_bounds__(256) void prep_w(const float* __restrict__ Wr,
                                              const float* __restrict__ Wk,
                                              const float* __restrict__ Wv,
                                              char* __restrict__ ws) {
    int id = blockIdx.x * 256 + threadIdx.x;
    if (id < 272 * 1024) {                       // W_read: 1024 x 1088, packed-frag
        int n = id / 272;
        int k = (id % 272) * 4;
        f32x4 w = *(const f32x4*)(Wr + (size_t)n * 1088 + k);
        uint2 q; q.x = pk(w.x, w.y); q.y = pk(w.z, w.w);
        int t = k >> 6;
        size_t off = ((size_t)((n >> 7) * 17 + t) << 14) + pf_addr(n & 127, k & 63);
        *(uint2*)(ws + off) = q;
    } else {                                     // Wk|Wv combined: 2048 x 128
        int j = id - 272 * 1024;
        int r = j >> 5;                          // 0..2047
        int k = (j & 31) << 2;                   // 0..124
        const float* src = (r < 1024) ? (Wk + (size_t)r * 128 + k)
                                      : (Wv + (size_t)(r - 1024) * 128 + k);
        f32x4 w = *(const f32x4*)src;
        uint2 q; q.x = pk(w.x, w.y); q.y = pk(w.z, w.w);
        size_t off = WS2_OFF + (size_t)r * W2_ROWB + ((k >> 6) << 7)
                   + (((k & 63) << 1) ^ ((r & 7) << 4));
        *(uint2*)(ws + off) = q;
    }
}

// ---------- fuse_a body (R8-identical math) ----------
__device__ __forceinline__
void fuse_body(int u, const float* __restrict__ S, const float* __restrict__ wsp,
               const float* __restrict__ whp, const float* __restrict__ whs,
               const float* __restrict__ wtg, char* __restrict__ a16) {
    int row = u / 272;
    int rem = u % 272;
    int ks = rem >> 4;
    int k4 = (rem & 15) << 2;

    const float* wbase; int wstr, wko;
    pick_w(ks, wsp, whp, whs, wtg, wbase, wstr, wko);

    f32x4 s4 = *(const f32x4*)(S + (size_t)row * 1088 + ks * 64 + k4);
    f32x4 w4 = *(const f32x4*)(wbase + (size_t)row * wstr + wko + k4);
    uint2 q; q.x = pk(s4.x + w4.x, s4.y + w4.y);
             q.y = pk(s4.z + w4.z, s4.w + w4.w);
    size_t off = ((size_t)((row >> 7) * 17 + ks) << 14) + pf_addr(row & 127, k4);
    *(uint2*)(a16 + off) = q;
}

// ---------- kv body (R8 gemm_kv with explicit mblk/nb) ----------
__device__ __forceinline__
void kv_body(int mblk, int nb, const float* __restrict__ lat,
             const char* __restrict__ ws2, float* __restrict__ outk,
             float* __restrict__ outv, char* lds) {
    char* Al = lds;
    char* Bl = lds + 16384;

    int m0 = mblk << 7;
    int nrow0 = nb << 7;
    float* out = (nb < 8) ? outk : outv;
    int n0 = (nb & 7) << 7;

    int tid = threadIdx.x;
    int lane = tid & 63, wid = tid >> 6;
    int wm = (wid >> 1) << 6, wn = (wid & 1) << 6;
    int lp = lane & 15, lg = lane >> 4;

    f32x4 acc[4][4] = {};

    for (int ks = 0; ks < 2; ++ks) {
        __syncthreads();
        {
            const char* wrow = ws2 + (size_t)nrow0 * W2_ROWB + ks * 128;
            #pragma unroll
            for (int c = 0; c < 4; ++c) {
                int s = c * 4096 + wid * 1024 + lane * 16;
                int n = s >> 7, cb = s & 127;
                gload_lds16(wrow + (size_t)n * W2_ROWB + cb,
                            Bl + c * 4096 + wid * 1024);
            }
        }
        #pragma unroll
        for (int i = 0; i < 8; ++i) {
            int u = i * 256 + tid;
            int row = u >> 4;
            int k4 = (u & 15) << 2;
            f32x4 s4 = *(const f32x4*)(lat + (size_t)(m0 + row) * 128 + ks * 64 + k4);
            uint2 q; q.x = pk(s4.x, s4.y); q.y = pk(s4.z, s4.w);
            *(uint2*)(Al + (row << 7) + ((k4 << 1) ^ ((row & 7) << 4))) = q;
        }
        __syncthreads();

        #pragma unroll
        for (int b = 0; b < 2; ++b) {
            Frag af[4], bf[4];
            #pragma unroll
            for (int f = 0; f < 4; ++f) {
                int ra = wm + f * 16 + lp;  int xa = (ra & 7) << 4;
                af[f].d[0] = *(const unsigned long long*)(Al + (ra << 7) + ((b * 64 + lg * 8) ^ xa));
                af[f].d[1] = *(const unsigned long long*)(Al + (ra << 7) + ((b * 64 + 32 + lg * 8) ^ xa));
                int rb = wn + f * 16 + lp;  int xb = (rb & 7) << 4;
                bf[f].d[0] = *(const unsigned long long*)(Bl + (rb << 7) + ((b * 64 + lg * 8) ^ xb));
                bf[f].d[1] = *(const unsigned long long*)(Bl + (rb << 7) + ((b * 64 + 32 + lg * 8) ^ xb));
            }
            #pragma unroll
            for (int i = 0; i < 4; ++i)
                #pragma unroll
                for (int j = 0; j < 4; ++j)
                    acc[i][j] = __builtin_amdgcn_mfma_f32_16x16x32_f16(af[i].v, bf[j].v, acc[i][j], 0, 0, 0);
        }
    }

    #pragma unroll
    for (int i = 0; i < 4; ++i)
        #pragma unroll
        for (int j = 0; j < 4; ++j) {
            int row = m0 + wm + i * 16 + (lg << 2);
            int col = n0 + wn + j * 16 + lp;
            float* p = out + (size_t)row * 1024 + col;
            #pragma unroll
            for (int r = 0; r < 4; ++r) p[(size_t)r * 1024] = acc[i][j][r];
        }
}

// ============ merged fuse_a || gemm_kv ============
// Groups of gsz blocks: 17 fuse-role + kvpg kv-role (kv blocks spread uniformly
// so read-stream (fuse) and write-stream (kv) are co-resident the whole time).
// kvpg=2: full kv (4096), grid 2048*19. kvpg=1: k-half only (2048), grid 2048*18.
__global__ __launch_bounds__(256, 2)
void fuse_kv(const float* __restrict__ S, const float* __restrict__ wsp,
             const float* __restrict__ whp, const float* __restrict__ whs,
             const float* __restrict__ wtg, char* __restrict__ a16,
             const float* __restrict__ lat, const char* __restrict__ ws2,
             float* __restrict__ outk, float* __restrict__ outv,
             int kvpg, int gsz) {
    __shared__ char lds[32768];
    int bid = blockIdx.x;
    int g = bid / gsz, slot = bid - g * gsz;
    if (slot < 17) {
        fuse_body((g * 17 + slot) * 256 + threadIdx.x, S, wsp, whp, whs, wtg, a16);
    } else {
        int idx = g * kvpg + (slot - 17);
        int mblk, nb;
        if (kvpg == 2) { int wg = (idx & 7) * 512 + (idx >> 3); mblk = wg >> 4; nb = wg & 15; }
        else           { int wg = (idx & 7) * 256 + (idx >> 3); mblk = wg >> 3; nb = wg & 7; }
        kv_body(mblk, nb, lat, ws2, outk, outv, lds);
    }
}

// v-half standalone (fallback path: runs after gemm_read frees the a16 region)
__global__ __launch_bounds__(256, 2)
void gemm_v(const float* __restrict__ lat, const char* __restrict__ ws2,
            float* __restrict__ outk, float* __restrict__ outv) {
    __shared__ char lds[32768];
    int idx = blockIdx.x;
    int wg = (idx & 7) * 256 + (idx >> 3);
    kv_body(wg >> 3, 8 + (wg & 7), lat, ws2, outk, outv, lds);
}

// ============ GEMM1: out = Af16 @ W_read^T — 4-phase/K-tile (R8-identical) ====
__global__ __launch_bounds__(512, 2)
void gemm_read(const char* __restrict__ a16, const char* __restrict__ wws,
               float* __restrict__ out) {
    extern __shared__ char lds[];                // 131072 B

    int bid = blockIdx.x;
    int wg   = (bid & 7) * 64 + (bid >> 3);      // bijective XCD swizzle (512%8==0)
    int mblk = wg >> 2, nblk = wg & 3;
    int m0 = mblk << 8, n0 = nblk << 8;

    int tid = threadIdx.x;
    int lane = tid & 63, wid = tid >> 6;
    int wm = (wid >> 2) << 7, wn = (wid & 3) << 6;   // wave tile: 128x64
    int lp = lane & 15, lg = lane >> 4;

    int aoff = (wid >> 2) * 16384;               // wave's A-half region
    int boff = 32768 + (wn >> 7) * 16384;        // wave's B-half region
    int cb64 = wn & 64;                          // col base within B-half

    const char* srcH[4];
    srcH[0] = a16 + ((size_t)((m0 >> 7) * 17) << 14);
    srcH[1] = srcH[0] + (17 << 14);
    srcH[2] = wws + ((size_t)((n0 >> 7) * 17) << 14);
    srcH[3] = srcH[2] + (17 << 14);

    f32x4 acc[8][4] = {};
    Frag af[4], bf[4];

#define STAGE(T, H, DB) do {                                               \
        const char* s_ = srcH[H] + ((size_t)(T) << 14);                    \
        char* d_ = lds + (DB) + (H) * 16384;                               \
        gload_lds16(s_ + tid * 16, d_ + tid * 16);                         \
        gload_lds16(s_ + 8192 + tid * 16, d_ + 8192 + tid * 16);           \
    } while (0)

#define LOADA(MH, KH, BB) do {                                             \
        _Pragma("unroll")                                                  \
        for (int f = 0; f < 4; ++f) {                                      \
            int r_ = (MH) * 64 + f * 16 + lp;                              \
            af[f] = *(const Frag*)(lds + (BB) + aoff + (r_ << 7)           \
                     + ((((((KH) << 2) | lg) ^ (r_ & 7))) << 4));          \
        }                                                                  \
    } while (0)

#define LOADB(KH, BB) do {                                                 \
        _Pragma("unroll")                                                  \
        for (int g = 0; g < 4; ++g) {                                      \
            int c_ = cb64 + g * 16 + lp;                                   \
            bf[g] = *(const Frag*)(lds + (BB) + boff + (c_ << 7)           \
                     + ((((((KH) << 2) | lg) ^ (c_ & 7))) << 4));          \
        }                                                                  \
    } while (0)

#define MFMA16(MH) do {                                                    \
        __builtin_amdgcn_s_setprio(1);                                     \
        _Pragma("unroll")                                                  \
        for (int f = 0; f < 4; ++f)                                        \
            _Pragma("unroll")                                              \
            for (int g = 0; g < 4; ++g)                                    \
                acc[(MH) * 4 + f][g] = __builtin_amdgcn_mfma_f32_16x16x32_f16( \
                    af[f].v, bf[g].v, acc[(MH) * 4 + f][g], 0, 0, 0);      \
        __builtin_amdgcn_s_setprio(0);                                     \
    } while (0)

    STAGE(0, 0, 0); STAGE(0, 1, 0); STAGE(0, 2, 0); STAGE(0, 3, 0);

    for (int t = 0; t < 16; ++t) {
        int BB = (t & 1) << 16;
        int NB = BB ^ 65536;
        STAGE(t + 1, 0, NB);
        asm volatile("s_waitcnt vmcnt(2)" ::: "memory");
        __builtin_amdgcn_s_barrier();
        LOADB(0, BB); LOADA(0, 0, BB);
        MFMA16(0);
        __builtin_amdgcn_s_barrier();
        LOADA(1, 0, BB);
        STAGE(t + 1, 1, NB);
        __builtin_amdgcn_s_barrier();
        MFMA16(1);
        __builtin_amdgcn_s_barrier();
        LOADB(1, BB); LOADA(0, 1, BB);
        STAGE(t + 1, 2, NB);
        __builtin_amdgcn_s_barrier();
        MFMA16(0);
        __builtin_amdgcn_s_barrier();
        LOADA(1, 1, BB);
        STAGE(t + 1, 3, NB);
        __builtin_amdgcn_s_barrier();
        MFMA16(1);
        __builtin_amdgcn_s_barrier();
    }
    {
        const int BB = 0;
        asm volatile("s_waitcnt vmcnt(0)" ::: "memory");
        __builtin_amdgcn_s_barrier();
        LOADB(0, BB); LOADA(0, 0, BB); MFMA16(0);
        __builtin_amdgcn_s_barrier();
        LOADA(1, 0, BB); MFMA16(1);
        __builtin_amdgcn_s_barrier();
        LOADB(1, BB); LOADA(0, 1, BB); MFMA16(0);
        __builtin_amdgcn_s_barrier();
        LOADA(1, 1, BB); MFMA16(1);
    }

    #pragma unroll
    for (int i = 0; i < 8; ++i)
        #pragma unroll
        for (int j = 0; j < 4; ++j) {
            int row = m0 + wm + i * 16 + (lg << 2);
            int col = n0 + wn + j * 16 + lp;
            float* p = out + (size_t)row * 1024 + col;
            #pragma unroll
            for (int r = 0; r < 4; ++r) p[(size_t)r * 1024] = acc[i][j][r];
        }
#undef STAGE
#undef LOADA
#undef LOADB
#undef MFMA16
}

// ============ host ============
extern "C" void kernel_launch(void* const* d_in, const int* in_sizes, int n_in,
                              void* d_out, int out_size, void* d_ws, size_t ws_size,
                              hipStream_t stream) {
    const float* S   = (const float*)d_in[0];
    const float* wsp = (const float*)d_in[1];
    const float* whp = (const float*)d_in[2];
    const float* whs = (const float*)d_in[3];
    const float* wtg = (const float*)d_in[4];
    const float* Wr  = (const float*)d_in[5];
    // d_in[6] = cache: fully overwritten by latent -> dead input
    const float* lat = (const float*)d_in[7];
    const float* Wk  = (const float*)d_in[8];
    const float* Wv  = (const float*)d_in[9];
    float* out = (float*)d_out;
    char*  ws  = (char*)d_ws;

    float* outk = out + 33554432ull;
    float* outv = out + 67108864ull;

    static bool lds_init = false;
    if (!lds_init) {
        hipFuncSetAttribute(reinterpret_cast<const void*>(gemm_read),
                            hipFuncAttributeMaxDynamicSharedMemorySize, 131072);
        lds_init = true;
    }

    const size_t A16_WS_OFF = (size_t)WS2_OFF + WS2_SZ;   // 2,752,512
    const size_t ws_need = A16_WS_OFF + A16_SZ;           // ~74 MB

    hipLaunchKernelGGL(prep_w, dim3(1344), dim3(256), 0, stream, Wr, Wk, Wv, ws);

    if (ws_size >= ws_need) {
        // a16 in workspace: merge fuse_a with FULL kv (k and v), 3 launches
        char* a16 = ws + A16_WS_OFF;
        hipLaunchKernelGGL(fuse_kv, dim3(2048 * 19), dim3(256), 0, stream,
                           S, wsp, whp, whs, wtg, a16,
                           lat, ws + WS2_OFF, outk, outv, 2, 19);
        hipLaunchKernelGGL(gemm_read, dim3(512), dim3(512), 131072, stream,
                           a16, ws, out);
    } else {
        // a16 aliases outv: merge fuse_a with the k-half only; v after gemm_read
        char* a16 = (char*)outv;
        hipLaunchKernelGGL(fuse_kv, dim3(2048 * 18), dim3(256), 0, stream,
                           S, wsp, whp, whs, wtg, a16,
                           lat, ws + WS2_OFF, outk, outv, 1, 18);
        hipLaunchKernelGGL(gemm_read, dim3(512), dim3(512), 131072, stream,
                           a16, ws, out);
        hipLaunchKernelGGL(gemm_v, dim3(2048), dim3(256), 0, stream,
                           lat, ws + WS2_OFF, outk, outv);
    }
}